// Round 5
// baseline (128.980 us; speedup 1.0000x reference)
//
#include <hip/hip_runtime.h>
#include <hip/hip_bf16.h>

// AttentivePooling: B=32, S=8192, C=256, MID=128, fp32 in/out.
// out[b,c] = sum_s softmax_s( tanh(x@W1+b1)@w2 )[b,s] * x[b,s,c]   (b2 shift-invariant)
//
// R5: barrier-free GEMM phase. A-fragments loaded global->VGPR directly
// (each x element is consumed by exactly one lane -> LDS gives no reuse),
// BK=32 chunks, 2-deep register prefetch, compiler-managed vmcnt waits.
// 1-term bf16 MFMA (x_hi * W_hi vs fp32 W fragments pre-rounded to bf16).

typedef __attribute__((ext_vector_type(8))) short short8;
typedef __attribute__((ext_vector_type(4))) float f32x4;
typedef unsigned short u16;

constexpr int Bb = 32;
constexpr int Ss = 8192;
constexpr int Cc = 256;
constexpr int MIDm = 128;
constexpr int BM = 128;              // rows per block
constexpr int NBLK = Bb * Ss / BM;   // 2048
constexpr int BPB = Ss / BM;         // 64 blocks per batch

__device__ __forceinline__ u16 f2bf(float f) {
  return __builtin_bit_cast(u16, __float2bfloat16(f));   // RNE
}

// ---- one-time prep: W fragments, frag-major (same layout as R4) ----
// t = wc*2048 + kcc*256 + nt*64 + lane  -> 8 bf16 (16B):
//   n = wc*64 + nt*16 + (lane&15),  k = kcc*32 + (lane>>4)*8 + e
__global__ __launch_bounds__(256) void wprep_kernel(
    const float* __restrict__ W1, u16* __restrict__ FB)
{
  const int t    = blockIdx.x * 256 + threadIdx.x;   // 0..4095
  const int lane = t & 63;
  const int nt   = (t >> 6) & 3;
  const int kcc  = (t >> 8) & 7;
  const int wc   = (t >> 11) & 1;
  const int n    = wc * 64 + nt * 16 + (lane & 15);
  const int k0   = kcc * 32 + (lane >> 4) * 8;
  union { u16 v[8]; short8 s; } u;
  #pragma unroll
  for (int e = 0; e < 8; ++e) u.v[e] = f2bf(W1[(size_t)(k0 + e) * MIDm + n]);
  *(short8*)(FB + (size_t)t * 8) = u.s;
}

// ---- fused: barrier-free MFMA scores -> block softmax -> weighted x partial ----
__global__ __launch_bounds__(256, 2) void fused_kernel(
    const float* __restrict__ x, const u16* __restrict__ FB,
    const float* __restrict__ b1, const float* __restrict__ w2,
    float* __restrict__ oPart, float* __restrict__ mPart, float* __restrict__ lPart)
{
  __shared__ float sScore[2][BM];
  __shared__ float sP[BM];
  __shared__ float sMB, sLB;
  __shared__ __align__(16) float sO[4][Cc];

  const int tid  = threadIdx.x;
  const int lane = tid & 63;
  const int w    = tid >> 6;
  const int wr   = w >> 1;
  const int wc   = w & 1;
  const int q    = lane >> 4;
  const int ln   = lane & 15;
  const int row0 = blockIdx.x * BM;

  // per-mt A row pointers: row = row0 + 64*wr + 16*mt + ln, cols q*8 + [0..7]
  const float* pA[4];
  #pragma unroll
  for (int mt = 0; mt < 4; ++mt)
    pA[mt] = x + (size_t)(row0 + 64 * wr + 16 * mt + ln) * Cc + q * 8;

  const u16* fb = FB + ((size_t)wc * 2048 + lane) * 8;

  // acc init with b1[col]
  f32x4 acc[4][4];
  #pragma unroll
  for (int nt = 0; nt < 4; ++nt) {
    float bj = b1[64 * wc + 16 * nt + ln];
    #pragma unroll
    for (int mt = 0; mt < 4; ++mt) {
      acc[mt][nt][0] = bj; acc[mt][nt][1] = bj; acc[mt][nt][2] = bj; acc[mt][nt][3] = bj;
    }
  }

  float4 A0[2][4], A1[2][4];   // [phase][mt] : 32 B of fp32 A per frag
  short8 Bf[2][4];             // [phase][nt]

  #define LOADA(ph, kk)                                                  \
    { _Pragma("unroll")                                                  \
      for (int mt = 0; mt < 4; ++mt) {                                   \
        const float* p = pA[mt] + (kk) * 32;                             \
        A0[ph][mt] = *(const float4*)p;                                  \
        A1[ph][mt] = *(const float4*)(p + 4);                            \
      } }
  #define LOADB(ph, kk)                                                  \
    { _Pragma("unroll")                                                  \
      for (int nt = 0; nt < 4; ++nt)                                     \
        Bf[ph][nt] = *(const short8*)(fb + ((size_t)(kk) * 256 + nt * 64) * 8); }

  // prologue: 2 chunks in flight
  LOADA(0, 0) LOADB(0, 0)
  LOADA(1, 1) LOADB(1, 1)

  #pragma unroll
  for (int kcc = 0; kcc < 8; ++kcc) {
    const int ph = kcc & 1;

    // convert A[ph] fp32 -> bf16 frags (the only wait in the loop)
    short8 af[4];
    #pragma unroll
    for (int mt = 0; mt < 4; ++mt) {
      union { u16 v[8]; short8 s; } t8;
      t8.v[0] = f2bf(A0[ph][mt].x); t8.v[1] = f2bf(A0[ph][mt].y);
      t8.v[2] = f2bf(A0[ph][mt].z); t8.v[3] = f2bf(A0[ph][mt].w);
      t8.v[4] = f2bf(A1[ph][mt].x); t8.v[5] = f2bf(A1[ph][mt].y);
      t8.v[6] = f2bf(A1[ph][mt].z); t8.v[7] = f2bf(A1[ph][mt].w);
      af[mt] = t8.s;
    }
    // A[ph] regs free -> issue chunk kcc+2 (in flight across next 2 iters)
    if (kcc < 6) LOADA(ph, kcc + 2)

    // MFMA (waits on Bf[ph], issued 2 iterations ago)
    #pragma unroll
    for (int nt = 0; nt < 4; ++nt)
      #pragma unroll
      for (int mt = 0; mt < 4; ++mt)
        acc[mt][nt] = __builtin_amdgcn_mfma_f32_16x16x32_bf16(
            af[mt], Bf[ph][nt], acc[mt][nt], 0, 0, 0);

    // Bf[ph] regs free -> issue chunk kcc+2 (L2-hot, ~2 iters of lead)
    if (kcc < 6) LOADB(ph, kcc + 2)
  }

  // ---- epilogue: score[r] = sum_col tanh(h)*w2[col] ----
  float w2v[4];
  #pragma unroll
  for (int nt = 0; nt < 4; ++nt) w2v[nt] = w2[64 * wc + 16 * nt + ln];

  float p[4][4];
  #pragma unroll
  for (int mt = 0; mt < 4; ++mt)
    #pragma unroll
    for (int r = 0; r < 4; ++r) p[mt][r] = 0.f;

  #pragma unroll
  for (int mt = 0; mt < 4; ++mt)
    #pragma unroll
    for (int nt = 0; nt < 4; ++nt)
      #pragma unroll
      for (int r = 0; r < 4; ++r)
        p[mt][r] += (1.0f - 2.0f / (__expf(2.0f * acc[mt][nt][r]) + 1.0f)) * w2v[nt];

  #pragma unroll
  for (int off = 1; off < 16; off <<= 1)
    #pragma unroll
    for (int mt = 0; mt < 4; ++mt)
      #pragma unroll
      for (int r = 0; r < 4; ++r)
        p[mt][r] += __shfl_xor(p[mt][r], off);

  if (ln == 0) {
    #pragma unroll
    for (int mt = 0; mt < 4; ++mt)
      #pragma unroll
      for (int r = 0; r < 4; ++r)
        sScore[wc][64 * wr + 16 * mt + 4 * q + r] = p[mt][r];
  }
  __syncthreads();

  // ---- block-local softmax partials ----
  if (tid < BM) sP[tid] = sScore[0][tid] + sScore[1][tid];
  __syncthreads();
  if (w == 0) {
    float a = sP[lane], b = sP[lane + 64];
    float m = fmaxf(a, b);
    #pragma unroll
    for (int off = 1; off < 64; off <<= 1) m = fmaxf(m, __shfl_xor(m, off));
    float e0 = __expf(a - m), e1 = __expf(b - m);
    sP[lane] = e0; sP[lane + 64] = e1;
    float s = e0 + e1;
    #pragma unroll
    for (int off = 1; off < 64; off <<= 1) s += __shfl_xor(s, off);
    if (lane == 0) { sMB = m; sLB = s; }
  }
  __syncthreads();

  // ---- weighted x partial: o[c] = sum_r sP[r] * x[row0+r][c]  (L2-hot re-read) ----
  const int c4 = tid & 63;
  const int rg = tid >> 6;
  const float* xo = x + (size_t)(row0 + rg * 32) * Cc + c4 * 4;
  float4 o = make_float4(0.f, 0.f, 0.f, 0.f);
  #pragma unroll 8
  for (int r = 0; r < 32; ++r) {
    float pw = sP[rg * 32 + r];
    float4 xv = *(const float4*)(xo + (size_t)r * Cc);
    o.x = fmaf(pw, xv.x, o.x);
    o.y = fmaf(pw, xv.y, o.y);
    o.z = fmaf(pw, xv.z, o.z);
    o.w = fmaf(pw, xv.w, o.w);
  }
  *(float4*)&sO[rg][c4 * 4] = o;
  __syncthreads();

  float oc = sO[0][tid] + sO[1][tid] + sO[2][tid] + sO[3][tid];
  oPart[(size_t)blockIdx.x * Cc + tid] = oc;
  if (tid == 0) { mPart[blockIdx.x] = sMB; lPart[blockIdx.x] = sLB; }
}

// ---- combine 64 block partials per batch (deterministic) ----
__global__ __launch_bounds__(256) void combine_kernel(
    const float* __restrict__ oPart, const float* __restrict__ mPart,
    const float* __restrict__ lPart, float* __restrict__ out)
{
  const int b = blockIdx.x;
  const int t = threadIdx.x;
  float M = -3.4e38f;
  for (int k = 0; k < BPB; ++k) M = fmaxf(M, mPart[b * BPB + k]);
  float num = 0.f, den = 0.f;
  for (int k = 0; k < BPB; ++k) {
    float wgt = __expf(mPart[b * BPB + k] - M);
    den += wgt * lPart[b * BPB + k];
    num = fmaf(wgt, oPart[(size_t)(b * BPB + k) * Cc + t], num);
  }
  out[b * Cc + t] = num / den;
}

extern "C" void kernel_launch(void* const* d_in, const int* in_sizes, int n_in,
                              void* d_out, int out_size, void* d_ws, size_t ws_size,
                              hipStream_t stream)
{
  const float* x  = (const float*)d_in[0];
  const float* W1 = (const float*)d_in[1];
  const float* b1 = (const float*)d_in[2];
  const float* w2 = (const float*)d_in[3];
  // d_in[4] = b2: unused (softmax shift-invariant)
  float* out = (float*)d_out;

  u16*   FB    = (u16*)d_ws;                                  // 64 KB frag-major W
  float* oPart = (float*)((char*)d_ws + 65536);               // 2 MB
  float* mPart = (float*)((char*)d_ws + 65536 + 2097152);     // 8 KB
  float* lPart = (float*)((char*)d_ws + 65536 + 2097152 + 8192);

  wprep_kernel<<<16, 256, 0, stream>>>(W1, FB);
  fused_kernel<<<NBLK, 256, 0, stream>>>(x, FB, b1, w2, oPart, mPart, lPart);
  combine_kernel<<<Bb, Cc, 0, stream>>>(oPart, mPart, lPart, out);
}

// Round 6
// 107.285 us; speedup vs baseline: 1.2022x; 1.2022x over previous
//
#include <hip/hip_runtime.h>
#include <hip/hip_bf16.h>

// AttentivePooling: B=32, S=8192, C=256, MID=128, fp32 in/out.
// out[b,c] = sum_s softmax_s( tanh(x@W1+b1)@w2 )[b,s] * x[b,s,c]   (b2 shift-invariant)
//
// R6: back to R4's global_load_lds DMA structure (compiler can't sink it),
// but BK=32 (16KB chunks) -> 38KB LDS -> 4 blocks/CU for latency overlap.
// Both-sides XOR swizzle (cb ^ ((row&7)<<4)) on 128B rows. 1-term bf16 MFMA.

typedef __attribute__((ext_vector_type(8))) short short8;
typedef __attribute__((ext_vector_type(4))) float f32x4;
typedef unsigned short u16;

constexpr int Bb = 32;
constexpr int Ss = 8192;
constexpr int Cc = 256;
constexpr int MIDm = 128;
constexpr int BM = 128;              // rows per block
constexpr int BK = 32;               // fp32 cols per chunk
constexpr int NCH = Cc / BK;         // 8 chunks
constexpr int NBLK = Bb * Ss / BM;   // 2048
constexpr int BPB = Ss / BM;         // 64 blocks per batch

__device__ __forceinline__ u16 f2bf(float f) {
  return __builtin_bit_cast(u16, __float2bfloat16(f));   // RNE
}

// ---- one-time prep: W fragments, frag-major ----
// t = wc*2048 + kcc*256 + nt*64 + lane  -> 8 bf16 (16B):
//   n = wc*64 + nt*16 + (lane&15),  k = kcc*32 + (lane>>4)*8 + e
__global__ __launch_bounds__(256) void wprep_kernel(
    const float* __restrict__ W1, u16* __restrict__ FB)
{
  const int t    = blockIdx.x * 256 + threadIdx.x;   // 0..4095
  const int lane = t & 63;
  const int nt   = (t >> 6) & 3;
  const int kcc  = (t >> 8) & 7;
  const int wc   = (t >> 11) & 1;
  const int n    = wc * 64 + nt * 16 + (lane & 15);
  const int k0   = kcc * 32 + (lane >> 4) * 8;
  union { u16 v[8]; short8 s; } u;
  #pragma unroll
  for (int e = 0; e < 8; ++e) u.v[e] = f2bf(W1[(size_t)(k0 + e) * MIDm + n]);
  *(short8*)(FB + (size_t)t * 8) = u.s;
}

// ---- fused: DMA-staged MFMA scores -> block softmax -> weighted x partial ----
__global__ __launch_bounds__(256, 4) void fused_kernel(
    const float* __restrict__ x, const u16* __restrict__ FB,
    const float* __restrict__ b1, const float* __restrict__ w2,
    float* __restrict__ oPart, float* __restrict__ mPart, float* __restrict__ lPart)
{
  __shared__ __align__(16) char sX[2][BM * BK * 4];   // 2 x 16KB, swizzled rows (128B)
  __shared__ float sScore[2][BM];
  __shared__ float sP[BM];
  __shared__ float sMB, sLB;
  __shared__ __align__(16) float sO[4][Cc];

  const int tid  = threadIdx.x;
  const int lane = tid & 63;
  const int w    = tid >> 6;
  const int wr   = w >> 1;
  const int wc   = w & 1;
  const int q    = lane >> 4;
  const int ln   = lane & 15;
  const int row0 = blockIdx.x * BM;

  // acc init with b1[col]
  f32x4 acc[4][4];
  #pragma unroll
  for (int nt = 0; nt < 4; ++nt) {
    float bj = b1[64 * wc + 16 * nt + ln];
    #pragma unroll
    for (int mt = 0; mt < 4; ++mt) {
      acc[mt][nt][0] = bj; acc[mt][nt][1] = bj; acc[mt][nt][2] = bj; acc[mt][nt][3] = bj;
    }
  }

  const u16* fb = FB + ((size_t)wc * 2048 + lane) * 8;
  #define LDFRAG(kcc, nt) (*(const short8*)(fb + ((size_t)(kcc) * 256 + (nt) * 64) * 8))

  // STAGE chunk kc into buffer buf. LDS byte L (row=L>>7, cb=L&127) holds
  // global col byte (cb ^ ((row&7)<<4)) of the chunk -> ds_read applies same XOR.
  #define STAGE(buf, kc)                                                              \
    {                                                                                 \
      _Pragma("unroll")                                                               \
      for (int r = 0; r < 4; ++r) {                                                   \
        int L   = r * 4096 + tid * 16;                                                \
        int row = L >> 7;                                                             \
        int cb  = (L & 127) ^ ((row & 7) << 4);                                       \
        const char* src = (const char*)x                                              \
            + ((size_t)(row0 + row) * Cc + (size_t)(kc) * BK) * 4 + cb;               \
        __builtin_amdgcn_global_load_lds(                                             \
            (const __attribute__((address_space(1))) void*)src,                       \
            (__attribute__((address_space(3))) void*)(&sX[buf][0] + L),               \
            16, 0, 0);                                                                \
      }                                                                               \
    }

  short8 bfr[2][4];   // ping-pong B fragments

  // prologue
  STAGE(0, 0);
  #pragma unroll
  for (int nt = 0; nt < 4; ++nt) bfr[0][nt] = LDFRAG(0, nt);
  __syncthreads();

  #pragma unroll
  for (int kc = 0; kc < NCH; ++kc) {
    const int cur = kc & 1;
    if (kc < NCH - 1) {
      STAGE(1 - cur, kc + 1);
      #pragma unroll
      for (int nt = 0; nt < 4; ++nt) bfr[1 - cur][nt] = LDFRAG(kc + 1, nt);
    }

    // compute chunk kc: per mt read A frag (swizzled), cvt, 4 MFMA
    #pragma unroll
    for (int mt = 0; mt < 4; ++mt) {
      const int row = 64 * wr + 16 * mt + ln;
      const int s   = (row & 7) << 4;
      const char* base = &sX[cur][0] + row * 128;
      float4 lo = *(const float4*)(base + ((q * 32) ^ s));
      float4 hi = *(const float4*)(base + ((q * 32 + 16) ^ s));
      union { u16 v[8]; short8 s8; } t8;
      t8.v[0] = f2bf(lo.x); t8.v[1] = f2bf(lo.y); t8.v[2] = f2bf(lo.z); t8.v[3] = f2bf(lo.w);
      t8.v[4] = f2bf(hi.x); t8.v[5] = f2bf(hi.y); t8.v[6] = f2bf(hi.z); t8.v[7] = f2bf(hi.w);
      #pragma unroll
      for (int nt = 0; nt < 4; ++nt)
        acc[mt][nt] = __builtin_amdgcn_mfma_f32_16x16x32_bf16(
            t8.s8, bfr[cur][nt], acc[mt][nt], 0, 0, 0);
    }
    if (kc < NCH - 1) __syncthreads();
  }

  // ---- epilogue: score[r] = sum_col tanh(h)*w2[col] ----
  float w2v[4];
  #pragma unroll
  for (int nt = 0; nt < 4; ++nt) w2v[nt] = w2[64 * wc + 16 * nt + ln];

  float p[4][4];
  #pragma unroll
  for (int mt = 0; mt < 4; ++mt)
    #pragma unroll
    for (int r = 0; r < 4; ++r) p[mt][r] = 0.f;

  #pragma unroll
  for (int mt = 0; mt < 4; ++mt)
    #pragma unroll
    for (int nt = 0; nt < 4; ++nt)
      #pragma unroll
      for (int r = 0; r < 4; ++r)
        p[mt][r] += (1.0f - 2.0f / (__expf(2.0f * acc[mt][nt][r]) + 1.0f)) * w2v[nt];

  #pragma unroll
  for (int off = 1; off < 16; off <<= 1)
    #pragma unroll
    for (int mt = 0; mt < 4; ++mt)
      #pragma unroll
      for (int r = 0; r < 4; ++r)
        p[mt][r] += __shfl_xor(p[mt][r], off);

  if (ln == 0) {
    #pragma unroll
    for (int mt = 0; mt < 4; ++mt)
      #pragma unroll
      for (int r = 0; r < 4; ++r)
        sScore[wc][64 * wr + 16 * mt + 4 * q + r] = p[mt][r];
  }
  __syncthreads();

  // ---- block-local softmax partials ----
  if (tid < BM) sP[tid] = sScore[0][tid] + sScore[1][tid];
  __syncthreads();
  if (w == 0) {
    float a = sP[lane], b = sP[lane + 64];
    float m = fmaxf(a, b);
    #pragma unroll
    for (int off = 1; off < 64; off <<= 1) m = fmaxf(m, __shfl_xor(m, off));
    float e0 = __expf(a - m), e1 = __expf(b - m);
    sP[lane] = e0; sP[lane + 64] = e1;
    float s = e0 + e1;
    #pragma unroll
    for (int off = 1; off < 64; off <<= 1) s += __shfl_xor(s, off);
    if (lane == 0) { sMB = m; sLB = s; }
  }
  __syncthreads();

  // ---- weighted x partial: o[c] = sum_r sP[r] * x[row0+r][c]  (L2-hot re-read) ----
  const int c4 = tid & 63;
  const int rg = tid >> 6;
  const float* xo = x + (size_t)(row0 + rg * 32) * Cc + c4 * 4;
  float4 o = make_float4(0.f, 0.f, 0.f, 0.f);
  #pragma unroll 8
  for (int r = 0; r < 32; ++r) {
    float pw = sP[rg * 32 + r];
    float4 xv = *(const float4*)(xo + (size_t)r * Cc);
    o.x = fmaf(pw, xv.x, o.x);
    o.y = fmaf(pw, xv.y, o.y);
    o.z = fmaf(pw, xv.z, o.z);
    o.w = fmaf(pw, xv.w, o.w);
  }
  *(float4*)&sO[rg][c4 * 4] = o;
  __syncthreads();

  float oc = sO[0][tid] + sO[1][tid] + sO[2][tid] + sO[3][tid];
  oPart[(size_t)blockIdx.x * Cc + tid] = oc;
  if (tid == 0) { mPart[blockIdx.x] = sMB; lPart[blockIdx.x] = sLB; }
}

// ---- combine 64 block partials per batch (deterministic) ----
__global__ __launch_bounds__(256) void combine_kernel(
    const float* __restrict__ oPart, const float* __restrict__ mPart,
    const float* __restrict__ lPart, float* __restrict__ out)
{
  const int b = blockIdx.x;
  const int t = threadIdx.x;
  float M = -3.4e38f;
  for (int k = 0; k < BPB; ++k) M = fmaxf(M, mPart[b * BPB + k]);
  float num = 0.f, den = 0.f;
  for (int k = 0; k < BPB; ++k) {
    float wgt = __expf(mPart[b * BPB + k] - M);
    den += wgt * lPart[b * BPB + k];
    num = fmaf(wgt, oPart[(size_t)(b * BPB + k) * Cc + t], num);
  }
  out[b * Cc + t] = num / den;
}

extern "C" void kernel_launch(void* const* d_in, const int* in_sizes, int n_in,
                              void* d_out, int out_size, void* d_ws, size_t ws_size,
                              hipStream_t stream)
{
  const float* x  = (const float*)d_in[0];
  const float* W1 = (const float*)d_in[1];
  const float* b1 = (const float*)d_in[2];
  const float* w2 = (const float*)d_in[3];
  // d_in[4] = b2: unused (softmax shift-invariant)
  float* out = (float*)d_out;

  u16*   FB    = (u16*)d_ws;                                  // 64 KB frag-major W
  float* oPart = (float*)((char*)d_ws + 65536);               // 2 MB
  float* mPart = (float*)((char*)d_ws + 65536 + 2097152);     // 8 KB
  float* lPart = (float*)((char*)d_ws + 65536 + 2097152 + 8192);

  wprep_kernel<<<16, 256, 0, stream>>>(W1, FB);
  fused_kernel<<<NBLK, 256, 0, stream>>>(x, FB, b1, w2, oPart, mPart, lPart);
  combine_kernel<<<Bb, Cc, 0, stream>>>(oPart, mPart, lPart, out);
}

// Round 7
// 95.356 us; speedup vs baseline: 1.3526x; 1.1251x over previous
//
#include <hip/hip_runtime.h>
#include <hip/hip_bf16.h>

// AttentivePooling: B=32, S=8192, C=256, MID=128, fp32 in/out.
// out[b,c] = sum_s softmax_s( tanh(x@W1+b1)@w2 )[b,s] * x[b,s,c]   (b2 shift-invariant)
//
// R7: counted-vmcnt pipeline (T3/T4). A and B both staged via global_load_lds
// DMA (so manual vmcnt counting is exact): STAGE(k+1); vmcnt(6); s_barrier;
// compute(k); s_barrier. Prefetch never drained. launch_bounds(256,3) (no spill).
// LDS 48KB (2x16KB A swizzled + 2x8KB B + epilogue overlay on A-buf0) -> 3 blocks/CU.

typedef __attribute__((ext_vector_type(8))) short short8;
typedef __attribute__((ext_vector_type(4))) float f32x4;
typedef unsigned short u16;

constexpr int Bb = 32;
constexpr int Ss = 8192;
constexpr int Cc = 256;
constexpr int MIDm = 128;
constexpr int BM = 128;              // rows per block
constexpr int BK = 32;               // fp32 cols per chunk
constexpr int NCH = Cc / BK;         // 8 chunks
constexpr int NBLK = Bb * Ss / BM;   // 2048
constexpr int BPB = Ss / BM;         // 64 blocks per batch

__device__ __forceinline__ u16 f2bf(float f) {
  return __builtin_bit_cast(u16, __float2bfloat16(f));   // RNE
}

// ---- one-time prep: W fragments, frag-major ----
// t = wc*2048 + kcc*256 + nt*64 + lane  -> 8 bf16 (16B):
//   n = wc*64 + nt*16 + (lane&15),  k = kcc*32 + (lane>>4)*8 + e
__global__ __launch_bounds__(256) void wprep_kernel(
    const float* __restrict__ W1, u16* __restrict__ FB)
{
  const int t    = blockIdx.x * 256 + threadIdx.x;   // 0..4095
  const int lane = t & 63;
  const int nt   = (t >> 6) & 3;
  const int kcc  = (t >> 8) & 7;
  const int wc   = (t >> 11) & 1;
  const int n    = wc * 64 + nt * 16 + (lane & 15);
  const int k0   = kcc * 32 + (lane >> 4) * 8;
  union { u16 v[8]; short8 s; } u;
  #pragma unroll
  for (int e = 0; e < 8; ++e) u.v[e] = f2bf(W1[(size_t)(k0 + e) * MIDm + n]);
  *(short8*)(FB + (size_t)t * 8) = u.s;
}

// ---- fused: counted-vmcnt DMA pipeline -> MFMA -> softmax -> weighted x ----
__global__ __launch_bounds__(256, 3) void fused_kernel(
    const float* __restrict__ x, const u16* __restrict__ FB,
    const float* __restrict__ b1, const float* __restrict__ w2,
    float* __restrict__ oPart, float* __restrict__ mPart, float* __restrict__ lPart)
{
  __shared__ __align__(16) char smem[49152];
  // [0,16K)   sX buf0 (swizzled 128B rows)   | epilogue overlay lives here
  // [16K,32K) sX buf1
  // [32K,40K) sB buf0   [40K,48K) sB buf1
  #define SXA(buf) (smem + (buf) * 16384)
  #define SBB(buf) (smem + 32768 + (buf) * 8192)

  const int tid  = threadIdx.x;
  const int lane = tid & 63;
  const int w    = tid >> 6;
  const int wr   = w >> 1;
  const int wc   = w & 1;
  const int q    = lane >> 4;
  const int ln   = lane & 15;
  const int row0 = blockIdx.x * BM;

  // acc init with b1[col]
  f32x4 acc[4][4];
  #pragma unroll
  for (int nt = 0; nt < 4; ++nt) {
    float bj = b1[64 * wc + 16 * nt + ln];
    #pragma unroll
    for (int mt = 0; mt < 4; ++mt) {
      acc[mt][nt][0] = bj; acc[mt][nt][1] = bj; acc[mt][nt][2] = bj; acc[mt][nt][3] = bj;
    }
  }

  // STAGE chunk kc into buffer buf: A (4 DMA) + B (2 DMA) = 6 loads/thread.
  // A: LDS byte L (row=L>>7, cb=L&127) holds global col byte cb^((row&7)<<4).
  // B: linear copy of FB's two 4KB half-chunks.
  #define STAGE_ALL(buf, kc)                                                          \
    {                                                                                 \
      _Pragma("unroll")                                                               \
      for (int r = 0; r < 4; ++r) {                                                   \
        int L   = r * 4096 + tid * 16;                                                \
        int row = L >> 7;                                                             \
        int cb  = (L & 127) ^ ((row & 7) << 4);                                       \
        const char* src = (const char*)x                                              \
            + ((size_t)(row0 + row) * Cc + (size_t)(kc) * BK) * 4 + cb;               \
        __builtin_amdgcn_global_load_lds(                                             \
            (const __attribute__((address_space(1))) void*)src,                       \
            (__attribute__((address_space(3))) void*)(SXA(buf) + L),                  \
            16, 0, 0);                                                                \
      }                                                                               \
      _Pragma("unroll")                                                               \
      for (int r = 0; r < 2; ++r) {                                                   \
        const char* srcb = (const char*)FB                                            \
            + ((size_t)r * 2048 + (size_t)(kc) * 256) * 16 + (size_t)tid * 16;        \
        __builtin_amdgcn_global_load_lds(                                             \
            (const __attribute__((address_space(1))) void*)srcb,                      \
            (__attribute__((address_space(3))) void*)(SBB(buf) + r * 4096 + tid * 16),\
            16, 0, 0);                                                                \
      }                                                                               \
    }

  // prologue: chunk 0 in flight
  STAGE_ALL(0, 0);

  #pragma unroll
  for (int kc = 0; kc < NCH; ++kc) {
    const int cur = kc & 1;
    if (kc < NCH - 1) STAGE_ALL(1 - cur, kc + 1);   // buf safe: bottom barrier of kc-1

    __builtin_amdgcn_sched_barrier(0);
    if (kc < NCH - 1) asm volatile("s_waitcnt vmcnt(6)");   // chunk kc landed; kc+1 flying
    else              asm volatile("s_waitcnt vmcnt(0)");   // last chunk: drain
    __builtin_amdgcn_sched_barrier(0);
    __builtin_amdgcn_s_barrier();                           // all threads' chunk kc visible
    __builtin_amdgcn_sched_barrier(0);

    // B fragments for this wave's column half
    const char* bb = SBB(cur) + wc * 4096 + lane * 16;
    short8 bfrag[4];
    #pragma unroll
    for (int nt = 0; nt < 4; ++nt)
      bfrag[nt] = *(const short8*)(bb + nt * 1024);

    // A fragments (swizzled read) + cvt + MFMA
    #pragma unroll
    for (int mt = 0; mt < 4; ++mt) {
      const int row = 64 * wr + 16 * mt + ln;
      const int s   = (row & 7) << 4;
      const char* base = SXA(cur) + row * 128;
      float4 lo = *(const float4*)(base + ((q * 32) ^ s));
      float4 hi = *(const float4*)(base + ((q * 32 + 16) ^ s));
      union { u16 v[8]; short8 s8; } t8;
      t8.v[0] = f2bf(lo.x); t8.v[1] = f2bf(lo.y); t8.v[2] = f2bf(lo.z); t8.v[3] = f2bf(lo.w);
      t8.v[4] = f2bf(hi.x); t8.v[5] = f2bf(hi.y); t8.v[6] = f2bf(hi.z); t8.v[7] = f2bf(hi.w);
      #pragma unroll
      for (int nt = 0; nt < 4; ++nt)
        acc[mt][nt] = __builtin_amdgcn_mfma_f32_16x16x32_bf16(
            t8.s8, bfrag[nt], acc[mt][nt], 0, 0, 0);
    }

    __builtin_amdgcn_sched_barrier(0);
    __builtin_amdgcn_s_barrier();                           // reads of buf[cur] done
  }

  // ---- epilogue overlay (aliases sX buf0; safe: buf0 last read at kc=6) ----
  float* sScore = (float*)smem;            // [2][128]
  float* sP     = (float*)(smem + 1024);   // [128]
  float* sO     = (float*)(smem + 2048);   // [4][256]
  float* sML    = (float*)(smem + 6144);   // m, l

  // score[r] = sum_col tanh(h)*w2[col]
  float w2v[4];
  #pragma unroll
  for (int nt = 0; nt < 4; ++nt) w2v[nt] = w2[64 * wc + 16 * nt + ln];

  float p[4][4];
  #pragma unroll
  for (int mt = 0; mt < 4; ++mt)
    #pragma unroll
    for (int r = 0; r < 4; ++r) p[mt][r] = 0.f;

  #pragma unroll
  for (int mt = 0; mt < 4; ++mt)
    #pragma unroll
    for (int nt = 0; nt < 4; ++nt)
      #pragma unroll
      for (int r = 0; r < 4; ++r)
        p[mt][r] += (1.0f - 2.0f / (__expf(2.0f * acc[mt][nt][r]) + 1.0f)) * w2v[nt];

  #pragma unroll
  for (int off = 1; off < 16; off <<= 1)
    #pragma unroll
    for (int mt = 0; mt < 4; ++mt)
      #pragma unroll
      for (int r = 0; r < 4; ++r)
        p[mt][r] += __shfl_xor(p[mt][r], off);

  if (ln == 0) {
    #pragma unroll
    for (int mt = 0; mt < 4; ++mt)
      #pragma unroll
      for (int r = 0; r < 4; ++r)
        sScore[wc * BM + 64 * wr + 16 * mt + 4 * q + r] = p[mt][r];
  }
  __syncthreads();

  // block-local softmax partials
  if (tid < BM) sP[tid] = sScore[tid] + sScore[BM + tid];
  __syncthreads();
  if (w == 0) {
    float a = sP[lane], b = sP[lane + 64];
    float m = fmaxf(a, b);
    #pragma unroll
    for (int off = 1; off < 64; off <<= 1) m = fmaxf(m, __shfl_xor(m, off));
    float e0 = __expf(a - m), e1 = __expf(b - m);
    sP[lane] = e0; sP[lane + 64] = e1;
    float s = e0 + e1;
    #pragma unroll
    for (int off = 1; off < 64; off <<= 1) s += __shfl_xor(s, off);
    if (lane == 0) { sML[0] = m; sML[1] = s; }
  }
  __syncthreads();

  // weighted x partial: o[c] = sum_r sP[r] * x[row0+r][c]  (L2-hot re-read)
  const int c4 = tid & 63;
  const int rg = tid >> 6;
  const float* xo = x + (size_t)(row0 + rg * 32) * Cc + c4 * 4;
  float4 o = make_float4(0.f, 0.f, 0.f, 0.f);
  #pragma unroll 8
  for (int r = 0; r < 32; ++r) {
    float pw = sP[rg * 32 + r];
    float4 xv = *(const float4*)(xo + (size_t)r * Cc);
    o.x = fmaf(pw, xv.x, o.x);
    o.y = fmaf(pw, xv.y, o.y);
    o.z = fmaf(pw, xv.z, o.z);
    o.w = fmaf(pw, xv.w, o.w);
  }
  *(float4*)&sO[rg * Cc + c4 * 4] = o;
  __syncthreads();

  float oc = sO[tid] + sO[Cc + tid] + sO[2 * Cc + tid] + sO[3 * Cc + tid];
  oPart[(size_t)blockIdx.x * Cc + tid] = oc;
  if (tid == 0) { mPart[blockIdx.x] = sML[0]; lPart[blockIdx.x] = sML[1]; }
}

// ---- combine 64 block partials per batch (deterministic) ----
__global__ __launch_bounds__(256) void combine_kernel(
    const float* __restrict__ oPart, const float* __restrict__ mPart,
    const float* __restrict__ lPart, float* __restrict__ out)
{
  const int b = blockIdx.x;
  const int t = threadIdx.x;
  float M = -3.4e38f;
  for (int k = 0; k < BPB; ++k) M = fmaxf(M, mPart[b * BPB + k]);
  float num = 0.f, den = 0.f;
  for (int k = 0; k < BPB; ++k) {
    float wgt = __expf(mPart[b * BPB + k] - M);
    den += wgt * lPart[b * BPB + k];
    num = fmaf(wgt, oPart[(size_t)(b * BPB + k) * Cc + t], num);
  }
  out[b * Cc + t] = num / den;
}

extern "C" void kernel_launch(void* const* d_in, const int* in_sizes, int n_in,
                              void* d_out, int out_size, void* d_ws, size_t ws_size,
                              hipStream_t stream)
{
  const float* x  = (const float*)d_in[0];
  const float* W1 = (const float*)d_in[1];
  const float* b1 = (const float*)d_in[2];
  const float* w2 = (const float*)d_in[3];
  // d_in[4] = b2: unused (softmax shift-invariant)
  float* out = (float*)d_out;

  u16*   FB    = (u16*)d_ws;                                  // 64 KB frag-major W
  float* oPart = (float*)((char*)d_ws + 65536);               // 2 MB
  float* mPart = (float*)((char*)d_ws + 65536 + 2097152);     // 8 KB
  float* lPart = (float*)((char*)d_ws + 65536 + 2097152 + 8192);

  wprep_kernel<<<16, 256, 0, stream>>>(W1, FB);
  fused_kernel<<<NBLK, 256, 0, stream>>>(x, FB, b1, w2, oPart, mPart, lPart);
  combine_kernel<<<Bb, Cc, 0, stream>>>(oPart, mPart, lPart, out);
}